// Round 13
// baseline (106.973 us; speedup 1.0000x reference)
//
#include <hip/hip_runtime.h>
#include <hip/hip_bf16.h>

#define BB 64
#define TT 1024
#define NN 512
#define LISTCAP (1u << 18)

static constexpr float THR = 0.15f;
static constexpr float SQ    = 6.0f / 127.0f;   // fixed quant scale (±6 sigma range)
static constexpr float INVSQ = 127.0f / 6.0f;

typedef __attribute__((ext_vector_type(4))) int i32x4;

// async global->LDS, 16B per lane; dest = wave-uniform base + lane*16 (HW rule)
__device__ __forceinline__ void gload16(const void* g, void* lds_dst) {
    __builtin_amdgcn_global_load_lds(
        (const __attribute__((address_space(1))) unsigned int*)g,
        (__attribute__((address_space(3))) unsigned int*)lds_dst, 16, 0, 0);
}

// ---------------- kernel T: streaming-read fp32->int8 transpose ----------------
// Fixes r12's measured binder: 256B-at-2KB-stride reads ran at 1.35 TB/s HBM
// (vs ~5 TB/s for full-row readers like r0's colsum_partial). Block (b,ts) reads a
// CONTIGUOUS 256 KB t-slab: thread (r=tid>>7, cq=tid&127) streams 32 float4s
// (t = 128ts+32r+i, cols 4cq..4cq+3; consecutive lanes = consecutive 16B).
// Quantize x = SQ*q + l (clamped +-127, residual MEASURED) and pack the thread's
// 4 cols x 32 contiguous k' = 32(r&1)+i entirely in registers (static unroll) into
// 8 uint4 slots of the swizzled page image byte(c',k') = c'*64 +
// (((k'>>4)^((c'>>1)&3))&3)*16 + (k'&15). 8x ds_write_b128 (cq-scrambled order
// spreads bank granules), one __syncthreads, then linear page drain (r12-proven:
// 16 pages x 4 KiB contiguous, 1 KB/wave-instr). Column sums are slab-PARTIALS
// (4 types x 4 cols per thread) stored to global scratch; colsum_reduce finishes.
__global__ __launch_bounds__(512) void transpose_quant(
    const float* __restrict__ x, char* __restrict__ xq, float* __restrict__ part) {
    __shared__ uint4 pages[4096];           // 64 KiB: 16 pages (g 0..7 x s' 0..1)
    int b = blockIdx.x, ts = blockIdx.y;
    int tid = threadIdx.x;
    int r = tid >> 7, cq = tid & 127;

    const float* xr = x + ((size_t)b * TT + 128 * ts + 32 * r) * NN + 4 * cq;

    float fa1[4] = {0.f, 0.f, 0.f, 0.f};
    float fa2[4] = {0.f, 0.f, 0.f, 0.f};
    float faq[4] = {0.f, 0.f, 0.f, 0.f};
    float fal[4] = {0.f, 0.f, 0.f, 0.f};
    unsigned pk[4][8];
    #pragma unroll
    for (int c = 0; c < 4; ++c)
        #pragma unroll
        for (int w = 0; w < 8; ++w) pk[c][w] = 0u;

    #pragma unroll
    for (int i = 0; i < 32; ++i) {
        float4 v = *(const float4*)(xr + (size_t)i * NN);
        #pragma unroll
        for (int cc = 0; cc < 4; ++cc) {
            float val = (cc == 0) ? v.x : (cc == 1) ? v.y : (cc == 2) ? v.z : v.w;
            fa1[cc] += val;
            fa2[cc] = fmaf(val, val, fa2[cc]);
            int q = __float2int_rn(val * INVSQ);
            q = q > 127 ? 127 : (q < -127 ? -127 : q);
            float qf = (float)q;
            faq[cc] = fmaf(qf, qf, faq[cc]);
            float lr = fmaf(qf, -SQ, val);      // measured residual
            fal[cc] = fmaf(lr, lr, fal[cc]);
            pk[cc][i >> 2] |= ((unsigned)(q & 255)) << (8 * (i & 3));
        }
    }

    // ---- 8 ds_write_b128: (cc, msub) order scrambled by cq to spread granules ----
    int g = cq >> 4;
    int sp = r >> 1;
    char* pbase = (char*)pages + ((g << 1) + sp) * 4096;
    unsigned mhi = ((unsigned)(r & 1)) << 1;        // slot high bit: k' = 32(r&1)+...
    #pragma unroll
    for (int w8 = 0; w8 < 8; ++w8) {
        int cc = (w8 + cq) & 3;
        int msub = (w8 >> 2) ^ ((cq >> 2) & 1);
        unsigned cp = (unsigned)((4 * (cq & 15)) + cc);   // c' within page
        unsigned slot = mhi + (unsigned)msub;
        unsigned off = cp * 64u + (((slot ^ ((cp >> 1) & 3u)) & 3u) << 4);
        *(uint4*)(pbase + off) = make_uint4(pk[cc][4 * msub], pk[cc][4 * msub + 1],
                                            pk[cc][4 * msub + 2], pk[cc][4 * msub + 3]);
    }

    // ---- slab partials -> global scratch (coalesced float4 per type) ----
    {
        size_t pb = ((size_t)(b * 8 + ts) * 4 + r) * 128 + cq;
        float4* p4 = (float4*)part;
        size_t stride = (size_t)BB * 8 * 4 * 128;
        p4[0 * stride + pb] = make_float4(fa1[0], fa1[1], fa1[2], fa1[3]);
        p4[1 * stride + pb] = make_float4(fa2[0], fa2[1], fa2[2], fa2[3]);
        p4[2 * stride + pb] = make_float4(faq[0], faq[1], faq[2], faq[3]);
        p4[3 * stride + pb] = make_float4(fal[0], fal[1], fal[2], fal[3]);
    }

    __syncthreads();

    // ---- linear drain: wave wv -> pages 2wv, 2wv+1 (contiguous 4 KiB each) ----
    int wv = tid >> 6, lane = tid & 63;
    #pragma unroll
    for (int pi = 0; pi < 2; ++pi) {
        int p = 2 * wv + pi;
        int pg = p >> 1, ps = p & 1;
        const char* src = (const char*)pages + p * 4096 + lane * 16;
        char* dst = xq + ((size_t)((b * 8 + pg) * 16) + 2 * ts + ps) * 4096 + lane * 16;
        #pragma unroll
        for (int it = 0; it < 4; ++it)
            *(uint4*)(dst + (size_t)it * 1024) =
                *(const uint4*)(src + (size_t)it * 1024);
    }
}

// ---------------- kernel T2: reduce slab partials -> s1, dv, nh, nl; zero fired ----
__global__ __launch_bounds__(512) void colsum_reduce(
    const float* __restrict__ part, float* __restrict__ s1, float* __restrict__ dv,
    float* __restrict__ nh, float* __restrict__ nl,
    unsigned* __restrict__ fired, unsigned* __restrict__ cnt) {
    int b = blockIdx.x;
    int c = threadIdx.x;                      // column 0..511
    int cq = c >> 2, cc = c & 3;
    size_t stride = (size_t)BB * 8 * 4 * 128 * 4;   // floats per type
    float acc[4] = {0.f, 0.f, 0.f, 0.f};
    #pragma unroll
    for (int t4 = 0; t4 < 4; ++t4) {
        float s = 0.f;
        for (int sl = 0; sl < 32; ++sl) {     // ts*4 + r
            size_t idx = t4 * stride + (((size_t)(b * 8) + (sl >> 2)) * 4 + (sl & 3))
                         * 512 + cq * 4 + cc;
            s += part[idx];
        }
        acc[t4] = s;
    }
    size_t o = (size_t)b * NN + c;
    s1[o] = acc[0];
    dv[o] = acc[1] - acc[0] * acc[0] * (1.0f / TT);   // exact unnormalized cov_ii
    nh[o] = SQ * sqrtf(acc[2]);                       // ||s*q||
    nl[o] = sqrtf(acc[3]);                            // ||residual||
    fired[o] = 0u;
    if (b == 0 && c == 0) *cnt = 0;
}

// ---------------- kernel B: i8 MFMA SYRK (r11/r12-verified, ~10us measured) ------
__global__ __launch_bounds__(256, 8) void corr_mfma(
    const char* __restrict__ xq, const float* __restrict__ s1,
    const float* __restrict__ dv, const float* __restrict__ nh,
    const float* __restrict__ nl, unsigned* __restrict__ fired,
    unsigned* __restrict__ cnt, unsigned* __restrict__ list) {
    __shared__ uint4 ldsbuf[1024];          // 16 KiB
    char* base = (char*)ldsbuf;

    int id = blockIdx.x;
    int swz = ((id & 7) * 288) + (id >> 3);   // 2304 = 8*288
    int b = swz / 36;
    int u = swz % 36;
    int ti = 0, rem = u;
    while (rem >= (8 - ti)) { rem -= (8 - ti); ++ti; }
    int tj = ti + rem;
    int i0 = ti * 64, j0 = tj * 64;
    bool diag = (ti == tj);

    int tid = threadIdx.x;
    int wave = tid >> 6, lane = tid & 63;
    int rl = lane & 15, kg = lane >> 4;

    const char* srcA = xq + ((size_t)(b * 8 + ti) * 16) * 4096 + tid * 16;
    const char* srcB = xq + ((size_t)(b * 8 + tj) * 16) * 4096 + tid * 16;

    auto STAGE = [&](int s, int buf) {
        char* d = base + (buf << 13) + wave * 1024;
        gload16(srcA + (size_t)s * 4096, d);
        if (!diag) gload16(srcB + (size_t)s * 4096, d + 4096);
    };

    int wr = wave >> 1, wc = wave & 1;
    bool skip_mm = diag && (wr == 1) && (wc == 0);

    unsigned aoff[2], boff[2];
    #pragma unroll
    for (int f = 0; f < 2; ++f) {
        unsigned ca = (unsigned)(32 * wr + 16 * f + rl);
        aoff[f] = ca * 64u + ((((unsigned)kg ^ ((ca >> 1) & 3u)) & 3u) << 4);
        unsigned cb2 = (unsigned)(32 * wc + 16 * f + rl);
        boff[f] = cb2 * 64u + ((((unsigned)kg ^ ((cb2 >> 1) & 3u)) & 3u) << 4);
    }
    unsigned bbase = diag ? 0u : 4096u;

    i32x4 acc[2][2];
    #pragma unroll
    for (int i = 0; i < 2; ++i)
        #pragma unroll
        for (int j = 0; j < 2; ++j)
            acc[i][j] = (i32x4)0;

    STAGE(0, 0);
    __syncthreads();

    for (int it = 0; it < 16; ++it) {
        if (it + 1 < 16) STAGE(it + 1, (it + 1) & 1);
        const char* cb = base + ((it & 1) << 13);
        if (!skip_mm) {
            i32x4 A[2], Bv[2];
            #pragma unroll
            for (int f = 0; f < 2; ++f) A[f] = *(const i32x4*)(cb + aoff[f]);
            #pragma unroll
            for (int f = 0; f < 2; ++f) Bv[f] = *(const i32x4*)(cb + bbase + boff[f]);
            #pragma unroll
            for (int fj = 0; fj < 2; ++fj)
                #pragma unroll
                for (int fi = 0; fi < 2; ++fi)
                    acc[fi][fj] = __builtin_amdgcn_mfma_i32_16x16x64_i8(
                        A[fi], Bv[fj], acc[fi][fj], 0, 0, 0);
        }
        __syncthreads();
    }

    // ---- epilogue ----
    const float thr2 = THR * THR;
    const float invT = 1.0f / TT;
    const float s2 = SQ * SQ;
    const float* s1b = s1 + (size_t)b * NN;
    const float* dvb = dv + (size_t)b * NN;
    const float* nhb = nh + (size_t)b * NN;
    const float* nlb = nl + (size_t)b * NN;
    unsigned* fb = fired + (size_t)b * NN;
    int rowb = i0 + 32 * wr + kg * 4;
    int colb = j0 + 32 * wc + rl;
    #pragma unroll
    for (int fj = 0; fj < 2; ++fj) {
        int gj = colb + 16 * fj;
        float sj = s1b[gj], djv = dvb[gj];
        float nhj = nhb[gj], nlj = nlb[gj];
        #pragma unroll
        for (int fi = 0; fi < 2; ++fi) {
            int gi0 = rowb + 16 * fi;
            #pragma unroll
            for (int r = 0; r < 4; ++r) {
                int gi = gi0 + r;
                if (gj > gi) {
                    float cc = s2 * (float)acc[fi][fj][r] - s1b[gi] * sj * invT;
                    float lim = thr2 * dvb[gi] * djv;
                    float nhi = nhb[gi], nli = nlb[gi];
                    float B = nli * nhj + nlj * nhi + nli * nlj
                              + 1e-3f * nhi * nhj;
                    float a = fabsf(cc);
                    float lo = a - B;
                    if (lo > 0.0f && lo * lo > lim) {
                        atomicOr(&fb[gi], 1u);
                    } else if ((a + B) * (a + B) > lim) {
                        unsigned idx = atomicAdd(cnt, 1u);
                        if (idx < LISTCAP)
                            list[idx] = ((unsigned)b << 18) | ((unsigned)gi << 9)
                                        | (unsigned)gj;
                    }
                }
            }
        }
    }
}

// ---------------- kernel B2: exact recompute of borderline pairs ----------------
__global__ __launch_bounds__(256) void cleanup_pairs(
    const float* __restrict__ x, const float* __restrict__ s1,
    const float* __restrict__ dv, const unsigned* __restrict__ cnt,
    const unsigned* __restrict__ list, unsigned* __restrict__ fired) {
    unsigned n = *cnt;
    if (n > LISTCAP) n = LISTCAP;
    int lane = threadIdx.x & 63;
    int gw = (blockIdx.x * 256 + threadIdx.x) >> 6;
    int nw = (gridDim.x * 256) >> 6;
    for (unsigned p = gw; p < n; p += nw) {
        unsigned e = list[p];
        int b = e >> 18, i = (e >> 9) & 511, j = e & 511;
        const float* xb = x + (size_t)b * TT * NN;
        double s = 0.0;
        for (int t = lane; t < TT; t += 64)
            s += (double)xb[(size_t)t * NN + i] * (double)xb[(size_t)t * NN + j];
        #pragma unroll
        for (int o = 32; o > 0; o >>= 1)
            s += __shfl_xor(s, o, 64);
        if (lane == 0) {
            double cov = s - (double)s1[(size_t)b * NN + i]
                             * (double)s1[(size_t)b * NN + j] / (double)TT;
            double lim = (double)THR * (double)THR
                         * (double)dv[(size_t)b * NN + i]
                         * (double)dv[(size_t)b * NN + j];
            if (cov * cov > lim) atomicOr(&fired[(size_t)b * NN + i], 1u);
        }
    }
}

// ---------------- kernel C: finalize mask ----------------
__global__ __launch_bounds__(512) void finalize_mask(
    const unsigned* __restrict__ fired, float* __restrict__ out) {
    int b = blockIdx.x;
    int n = threadIdx.x;
    unsigned f = fired[(size_t)b * NN + n];
    __shared__ int wsum[8];
    unsigned long long m = __ballot(f != 0u);
    int lane = n & 63;
    int w = n >> 6;
    if (lane == 0) wsum[w] = __popcll(m);
    __syncthreads();
    int cnt = 0;
    #pragma unroll
    for (int i = 0; i < 8; ++i) cnt += wsum[i];
    float val = (cnt == 0) ? 1.0f : ((cnt == 1) ? (f ? 1.0f : 0.0f) : 0.0f);
    out[(size_t)b * NN + n] = val;
}

extern "C" void kernel_launch(void* const* d_in, const int* in_sizes, int n_in,
                              void* d_out, int out_size, void* d_ws, size_t ws_size,
                              hipStream_t stream) {
    const float* x = (const float*)d_in[0];
    float* out = (float*)d_out;

    // ws layout (~50 MB)
    char* xq = (char*)d_ws;                              // 32 MB blocked pages
    float* part = (float*)(xq + (size_t)BB * NN * TT);   // 4*64*8*4*512 f = 16 MB
    float* s1 = part + (size_t)4 * BB * 8 * 4 * 512;     // B*N
    float* dv = s1 + (size_t)BB * NN;                    // B*N
    float* nh = dv + (size_t)BB * NN;                    // B*N
    float* nl = nh + (size_t)BB * NN;                    // B*N
    unsigned* fired = (unsigned*)(nl + (size_t)BB * NN); // B*N
    unsigned* cnt   = fired + (size_t)BB * NN;           // 16 (padded)
    unsigned* list  = cnt + 16;                          // LISTCAP

    transpose_quant<<<dim3(BB, 8), 512, 0, stream>>>(x, xq, part);
    colsum_reduce<<<BB, 512, 0, stream>>>(part, s1, dv, nh, nl, fired, cnt);
    corr_mfma<<<dim3(2304), 256, 0, stream>>>(xq, s1, dv, nh, nl, fired, cnt, list);
    cleanup_pairs<<<128, 256, 0, stream>>>(x, s1, dv, cnt, list, fired);
    finalize_mask<<<BB, 512, 0, stream>>>(fired, out);
}

// Round 14
// 92.146 us; speedup vs baseline: 1.1609x; 1.1609x over previous
//
#include <hip/hip_runtime.h>
#include <hip/hip_bf16.h>

#define BB 64
#define TT 1024
#define NN 512
#define LISTCAP (1u << 18)

static constexpr float THR = 0.15f;
static constexpr float SQ    = 6.0f / 127.0f;   // fixed quant scale (±6 sigma range)
static constexpr float INVSQ = 127.0f / 6.0f;

typedef __attribute__((ext_vector_type(4))) int i32x4;

// async global->LDS, 16B per lane; dest = wave-uniform base + lane*16 (HW rule)
__device__ __forceinline__ void gload16(const void* g, void* lds_dst) {
    __builtin_amdgcn_global_load_lds(
        (const __attribute__((address_space(1))) unsigned int*)g,
        (__attribute__((address_space(3))) unsigned int*)lds_dst, 16, 0, 0);
}

// ---------------- kernel T: r6-skeleton colsum + fp32->int8 page transpose -------
// EXACT r6 structure (measured ~12us in r9: shared tile, col-slice reads,
// 2x syncthreads per tc, wave-per-page contiguous drain) emitting int8 pages.
// Page format (r11/r12-verified, corr reads it unchanged):
//   page (b,g,s) 4 KiB: byte(c',k') = c'*64 + (((k'>>4)^((c'>>1)&3))&3)*16 + (k'&15)
// Thread (w,l): col n0+l (c'=l), per i writes k' = 8w..8w+7 of page i as ONE
// ds_write_b64 at l*64 + (((w>>1)^((l>>1)&3))<<4) + (w&1)*8  [static offsets only,
// rule #20 safe]. Bank check: 8 consecutive lanes hit all 8 bank-quads once
// (16(l&1) + 4*((w>>1)^((l>>1)&3))) -> conflict-free (r13's 262K conflicts fixed).
// Drain = verbatim page copy (pages stored as LDS image; 1 KB/wave-instr).
// Quant x = SQ*q + l_res (clamped +-127), residual MEASURED; nv=||x||, nl=||l_res||
// -> r5-form Cauchy-Schwarz bound downstream. Zeroes fired/cnt.
__global__ __launch_bounds__(512) void transpose_colsum(
    const float* __restrict__ x, char* __restrict__ xq,
    float* __restrict__ s1, float* __restrict__ dv,
    float* __restrict__ nv, float* __restrict__ nl,
    unsigned* __restrict__ fired, unsigned* __restrict__ cnt) {
    __shared__ uint4 tile[2048];            // 32 KiB = 8 pages x 4 KiB
    __shared__ float red[3][8][64];         // 6 KiB
    int b = blockIdx.x, ng = blockIdx.y;
    int n0 = ng * 64;
    int tid = threadIdx.x, w = tid >> 6, l = tid & 63;
    const float* xb = x + (size_t)b * TT * NN + n0 + l;
    float a1 = 0.f, a2 = 0.f, al = 0.f;
    if (b == 0 && ng == 0 && tid == 64) *cnt = 0;

    unsigned sw4 = ((((unsigned)w >> 1) ^ (((unsigned)l >> 1) & 3u)) & 3u);
    unsigned wroff = (unsigned)l * 64u + (sw4 << 4) + ((unsigned)(w & 1)) * 8u;

    for (int tc = 0; tc < 2; ++tc) {
        #pragma unroll
        for (int i = 0; i < 8; ++i) {
            int t0 = tc * 512 + i * 64 + w * 8;
            unsigned lo = 0, hi = 0;
            #pragma unroll
            for (int j = 0; j < 8; ++j) {
                float v = xb[(size_t)(t0 + j) * NN];
                a1 += v;
                a2 = fmaf(v, v, a2);
                int q = __float2int_rn(v * INVSQ);
                q = q > 127 ? 127 : (q < -127 ? -127 : q);
                float lr = fmaf((float)q, -SQ, v);   // measured residual (exact-ish)
                al = fmaf(lr, lr, al);
                unsigned byte = (unsigned)(q & 255);
                if (j < 4) lo |= byte << (8 * j);
                else       hi |= byte << (8 * (j - 4));
            }
            *(uint2*)((char*)tile + i * 4096 + wroff) = make_uint2(lo, hi);
        }
        __syncthreads();
        // drain: wave w -> page w (contiguous 4 KiB, verbatim LDS image)
        {
            const char* src = (const char*)tile + w * 4096 + l * 16;
            char* dst = xq + ((size_t)((b * 8 + ng) * 16) + tc * 8 + w) * 4096 + l * 16;
            #pragma unroll
            for (int it = 0; it < 4; ++it)
                *(uint4*)(dst + (size_t)it * 1024) =
                    *(const uint4*)(src + (size_t)it * 1024);
        }
        __syncthreads();
    }
    red[0][w][l] = a1; red[1][w][l] = a2; red[2][w][l] = al;
    __syncthreads();
    if (tid < 64) {
        float r1 = 0.f, r2 = 0.f, rl = 0.f;
        #pragma unroll
        for (int k = 0; k < 8; ++k) {
            r1 += red[0][k][tid]; r2 += red[1][k][tid]; rl += red[2][k][tid];
        }
        size_t o = (size_t)b * NN + n0 + tid;
        s1[o] = r1;
        dv[o] = r2 - r1 * r1 * (1.0f / TT);   // exact unnormalized cov_ii
        nv[o] = sqrtf(r2);                    // ||x_col||
        nl[o] = sqrtf(rl);                    // ||residual||
        fired[o] = 0u;
    }
}

// ---------------- kernel B: i8 MFMA SYRK (r11/r12-verified, ~10us measured) ------
// 64x64 tile per 256-thr block: 2304 blocks (XCD-chunked swizzle -> per-XCD
// working set 4 MB = L2-resident), 4 waves of 32x32, dbuf LDS 16 KiB. KT=64 via
// mfma_i32_16x16x64_i8, 16 K-steps. 1 contiguous gload16/wave/panel per step.
// 2-phase: STAGE(t+1,buf^1) -> COMPUTE(buf) -> __syncthreads. i32 accum exact.
// Epilogue: c = SQ^2*dot_q - s1_i*s1_j/T; B = nl_i*nv_j + nl_j*nv_i + 3*nl_i*nl_j
// + 1e-3*nv_i*nv_j (||h|| <= nv+nl triangle bound); uncertain -> exact cleanup.
__global__ __launch_bounds__(256, 8) void corr_mfma(
    const char* __restrict__ xq, const float* __restrict__ s1,
    const float* __restrict__ dv, const float* __restrict__ nv,
    const float* __restrict__ nl, unsigned* __restrict__ fired,
    unsigned* __restrict__ cnt, unsigned* __restrict__ list) {
    __shared__ uint4 ldsbuf[1024];          // 16 KiB
    char* base = (char*)ldsbuf;

    int id = blockIdx.x;
    int swz = ((id & 7) * 288) + (id >> 3);   // 2304 = 8*288
    int b = swz / 36;
    int u = swz % 36;
    int ti = 0, rem = u;
    while (rem >= (8 - ti)) { rem -= (8 - ti); ++ti; }
    int tj = ti + rem;
    int i0 = ti * 64, j0 = tj * 64;
    bool diag = (ti == tj);

    int tid = threadIdx.x;
    int wave = tid >> 6, lane = tid & 63;
    int rl = lane & 15, kg = lane >> 4;

    const char* srcA = xq + ((size_t)(b * 8 + ti) * 16) * 4096 + tid * 16;
    const char* srcB = xq + ((size_t)(b * 8 + tj) * 16) * 4096 + tid * 16;

    auto STAGE = [&](int s, int buf) {
        char* d = base + (buf << 13) + wave * 1024;
        gload16(srcA + (size_t)s * 4096, d);
        if (!diag) gload16(srcB + (size_t)s * 4096, d + 4096);
    };

    int wr = wave >> 1, wc = wave & 1;
    bool skip_mm = diag && (wr == 1) && (wc == 0);

    unsigned aoff[2], boff[2];
    #pragma unroll
    for (int f = 0; f < 2; ++f) {
        unsigned ca = (unsigned)(32 * wr + 16 * f + rl);
        aoff[f] = ca * 64u + ((((unsigned)kg ^ ((ca >> 1) & 3u)) & 3u) << 4);
        unsigned cb2 = (unsigned)(32 * wc + 16 * f + rl);
        boff[f] = cb2 * 64u + ((((unsigned)kg ^ ((cb2 >> 1) & 3u)) & 3u) << 4);
    }
    unsigned bbase = diag ? 0u : 4096u;

    i32x4 acc[2][2];
    #pragma unroll
    for (int i = 0; i < 2; ++i)
        #pragma unroll
        for (int j = 0; j < 2; ++j)
            acc[i][j] = (i32x4)0;

    STAGE(0, 0);
    __syncthreads();

    for (int it = 0; it < 16; ++it) {
        if (it + 1 < 16) STAGE(it + 1, (it + 1) & 1);
        const char* cb = base + ((it & 1) << 13);
        if (!skip_mm) {
            i32x4 A[2], Bv[2];
            #pragma unroll
            for (int f = 0; f < 2; ++f) A[f] = *(const i32x4*)(cb + aoff[f]);
            #pragma unroll
            for (int f = 0; f < 2; ++f) Bv[f] = *(const i32x4*)(cb + bbase + boff[f]);
            #pragma unroll
            for (int fj = 0; fj < 2; ++fj)
                #pragma unroll
                for (int fi = 0; fi < 2; ++fi)
                    acc[fi][fj] = __builtin_amdgcn_mfma_i32_16x16x64_i8(
                        A[fi], Bv[fj], acc[fi][fj], 0, 0, 0);
        }
        __syncthreads();
    }

    // ---- epilogue ----
    const float thr2 = THR * THR;
    const float invT = 1.0f / TT;
    const float s2 = SQ * SQ;
    const float* s1b = s1 + (size_t)b * NN;
    const float* dvb = dv + (size_t)b * NN;
    const float* nvb = nv + (size_t)b * NN;
    const float* nlb = nl + (size_t)b * NN;
    unsigned* fb = fired + (size_t)b * NN;
    int rowb = i0 + 32 * wr + kg * 4;
    int colb = j0 + 32 * wc + rl;
    #pragma unroll
    for (int fj = 0; fj < 2; ++fj) {
        int gj = colb + 16 * fj;
        float sj = s1b[gj], djv = dvb[gj];
        float nvj = nvb[gj], nlj = nlb[gj];
        #pragma unroll
        for (int fi = 0; fi < 2; ++fi) {
            int gi0 = rowb + 16 * fi;
            #pragma unroll
            for (int r = 0; r < 4; ++r) {
                int gi = gi0 + r;
                if (gj > gi) {
                    float cc = s2 * (float)acc[fi][fj][r] - s1b[gi] * sj * invT;
                    float lim = thr2 * dvb[gi] * djv;
                    float nvi = nvb[gi], nli = nlb[gi];
                    float B = nli * nvj + nlj * nvi + 3.0f * nli * nlj
                              + 1e-3f * nvi * nvj;
                    float a = fabsf(cc);
                    float lo = a - B;
                    if (lo > 0.0f && lo * lo > lim) {
                        atomicOr(&fb[gi], 1u);
                    } else if ((a + B) * (a + B) > lim) {
                        unsigned idx = atomicAdd(cnt, 1u);
                        if (idx < LISTCAP)
                            list[idx] = ((unsigned)b << 18) | ((unsigned)gi << 9)
                                        | (unsigned)gj;
                    }
                }
            }
        }
    }
}

// ---------------- kernel B2: exact recompute of borderline pairs ----------------
__global__ __launch_bounds__(256) void cleanup_pairs(
    const float* __restrict__ x, const float* __restrict__ s1,
    const float* __restrict__ dv, const unsigned* __restrict__ cnt,
    const unsigned* __restrict__ list, unsigned* __restrict__ fired) {
    unsigned n = *cnt;
    if (n > LISTCAP) n = LISTCAP;
    int lane = threadIdx.x & 63;
    int gw = (blockIdx.x * 256 + threadIdx.x) >> 6;
    int nw = (gridDim.x * 256) >> 6;
    for (unsigned p = gw; p < n; p += nw) {
        unsigned e = list[p];
        int b = e >> 18, i = (e >> 9) & 511, j = e & 511;
        const float* xb = x + (size_t)b * TT * NN;
        double s = 0.0;
        for (int t = lane; t < TT; t += 64)
            s += (double)xb[(size_t)t * NN + i] * (double)xb[(size_t)t * NN + j];
        #pragma unroll
        for (int o = 32; o > 0; o >>= 1)
            s += __shfl_xor(s, o, 64);
        if (lane == 0) {
            double cov = s - (double)s1[(size_t)b * NN + i]
                             * (double)s1[(size_t)b * NN + j] / (double)TT;
            double lim = (double)THR * (double)THR
                         * (double)dv[(size_t)b * NN + i]
                         * (double)dv[(size_t)b * NN + j];
            if (cov * cov > lim) atomicOr(&fired[(size_t)b * NN + i], 1u);
        }
    }
}

// ---------------- kernel C: finalize mask ----------------
__global__ __launch_bounds__(512) void finalize_mask(
    const unsigned* __restrict__ fired, float* __restrict__ out) {
    int b = blockIdx.x;
    int n = threadIdx.x;
    unsigned f = fired[(size_t)b * NN + n];
    __shared__ int wsum[8];
    unsigned long long m = __ballot(f != 0u);
    int lane = n & 63;
    int w = n >> 6;
    if (lane == 0) wsum[w] = __popcll(m);
    __syncthreads();
    int cnt = 0;
    #pragma unroll
    for (int i = 0; i < 8; ++i) cnt += wsum[i];
    float val = (cnt == 0) ? 1.0f : ((cnt == 1) ? (f ? 1.0f : 0.0f) : 0.0f);
    out[(size_t)b * NN + n] = val;
}

extern "C" void kernel_launch(void* const* d_in, const int* in_sizes, int n_in,
                              void* d_out, int out_size, void* d_ws, size_t ws_size,
                              hipStream_t stream) {
    const float* x = (const float*)d_in[0];
    float* out = (float*)d_out;

    // ws layout (~34 MB)
    char* xq = (char*)d_ws;                              // BB*8*16*4096 = 32 MB
    float* s1 = (float*)(xq + (size_t)BB * NN * TT);     // B*N
    float* dv = s1 + (size_t)BB * NN;                    // B*N
    float* nv = dv + (size_t)BB * NN;                    // B*N
    float* nl = nv + (size_t)BB * NN;                    // B*N
    unsigned* fired = (unsigned*)(nl + (size_t)BB * NN); // B*N
    unsigned* cnt   = fired + (size_t)BB * NN;           // 16 (padded)
    unsigned* list  = cnt + 16;                          // LISTCAP

    transpose_colsum<<<dim3(BB, 8), 512, 0, stream>>>(x, xq, s1, dv, nv, nl,
                                                      fired, cnt);
    corr_mfma<<<dim3(2304), 256, 0, stream>>>(xq, s1, dv, nv, nl, fired, cnt, list);
    cleanup_pairs<<<128, 256, 0, stream>>>(x, s1, dv, cnt, list, fired);
    finalize_mask<<<BB, 512, 0, stream>>>(fired, out);
}